// Round 7
// baseline (388.552 us; speedup 1.0000x reference)
//
#include <hip/hip_runtime.h>
#include <hip/hip_bf16.h>

#define N_ROWS 65536
#define DIM    512
#define KCLS   512

typedef __bf16 bf16x8 __attribute__((ext_vector_type(8)));
typedef float  f32x16 __attribute__((ext_vector_type(16)));

__device__ __forceinline__ float bf2f(ushort u) {
    union { unsigned int i; float f; } v; v.i = ((unsigned int)u) << 16; return v.f;
}

// ---------- Kernel 1: normalize rows -> bf16 embb + label histogram --------
__global__ __launch_bounds__(256) void rnorm_embb_kernel(
    const float* __restrict__ emb, const int* __restrict__ labels,
    ushort* __restrict__ embb, int* __restrict__ counts)
{
    const int tid  = threadIdx.x;
    const int wave = tid >> 6;
    const int lane = tid & 63;
    const int row  = blockIdx.x * 4 + wave;

    const float4* ep = (const float4*)(emb + (size_t)row * DIM + lane * 8);
    const float4 e0 = ep[0], e1 = ep[1];
    float ss = e0.x*e0.x + e0.y*e0.y + e0.z*e0.z + e0.w*e0.w
             + e1.x*e1.x + e1.y*e1.y + e1.z*e1.z + e1.w*e1.w;
    #pragma unroll
    for (int off = 1; off < 64; off <<= 1)
        ss += __shfl_xor(ss, off, 64);
    const float rn = 1.0f / fmaxf(sqrtf(ss), 1e-12f);

    bf16x8 h;
    h[0] = (__bf16)(e0.x * rn); h[1] = (__bf16)(e0.y * rn);
    h[2] = (__bf16)(e0.z * rn); h[3] = (__bf16)(e0.w * rn);
    h[4] = (__bf16)(e1.x * rn); h[5] = (__bf16)(e1.y * rn);
    h[6] = (__bf16)(e1.z * rn); h[7] = (__bf16)(e1.w * rn);
    *(bf16x8*)(embb + (size_t)row * DIM + lane * 8) = h;

    if (lane == 0) atomicAdd(&counts[labels[row]], 1);
}

// ---------- Kernel 2: exclusive scan of counts + zero loss_acc -------------
__global__ __launch_bounds__(512) void scan_kernel(
    const int* __restrict__ counts, int* __restrict__ offs,
    int* __restrict__ cursors, float* __restrict__ loss_acc)
{
    __shared__ int tmp[KCLS];
    const int t = threadIdx.x;
    tmp[t] = counts[t];
    __syncthreads();
    #pragma unroll
    for (int off = 1; off < KCLS; off <<= 1) {
        int v = (t >= off) ? tmp[t - off] : 0;
        __syncthreads();
        tmp[t] += v;
        __syncthreads();
    }
    offs[t]    = tmp[t] - counts[t];
    cursors[t] = 0;
    if (t == 0) loss_acc[0] = 0.f;
}

// ---------- Kernel 3: counting-sort scatter --------------------------------
__global__ __launch_bounds__(256) void scatter_kernel(
    const int* __restrict__ labels, const int* __restrict__ offs,
    int* __restrict__ cursors, int* __restrict__ order)
{
    const int i = blockIdx.x * 256 + threadIdx.x;
    const int l = labels[i];
    const int pos = atomicAdd(&cursors[l], 1);
    order[offs[l] + pos] = i;
}

// ---------- Kernel 4: per-class sums & bf16 centroids ----------------------
__global__ __launch_bounds__(256) void class_sum_kernel(
    const ushort* __restrict__ embb,
    const int* __restrict__ counts, const int* __restrict__ offs,
    const int* __restrict__ order,
    float* __restrict__ sums, ushort* __restrict__ centb)
{
    __shared__ float part[4][DIM];

    const int cls  = blockIdx.x;
    const int tid  = threadIdx.x;
    const int wave = tid >> 6;
    const int lane = tid & 63;
    const int cnt  = counts[cls];
    const int base = offs[cls];
    const int d8   = lane * 8;

    float a[8] = {};
    float b2[8] = {};
    int j = wave;
    for (; j + 4 < cnt; j += 8) {       // 2 independent gather chains in flight
        const int r1 = order[base + j];
        const int r2 = order[base + j + 4];
        const uint4 u1 = *(const uint4*)(embb + (size_t)r1 * DIM + d8);
        const uint4 u2 = *(const uint4*)(embb + (size_t)r2 * DIM + d8);
        const ushort* s1 = (const ushort*)&u1;
        const ushort* s2 = (const ushort*)&u2;
        #pragma unroll
        for (int q = 0; q < 8; ++q) { a[q] += bf2f(s1[q]); b2[q] += bf2f(s2[q]); }
    }
    if (j < cnt) {
        const int r = order[base + j];
        const uint4 u = *(const uint4*)(embb + (size_t)r * DIM + d8);
        const ushort* s1 = (const ushort*)&u;
        #pragma unroll
        for (int q = 0; q < 8; ++q) a[q] += bf2f(s1[q]);
    }
    #pragma unroll
    for (int q = 0; q < 8; ++q) part[wave][d8 + q] = a[q] + b2[q];
    __syncthreads();

    const int d0 = tid * 2;
    const float s0 = part[0][d0]   + part[1][d0]   + part[2][d0]   + part[3][d0];
    const float s1 = part[0][d0+1] + part[1][d0+1] + part[2][d0+1] + part[3][d0+1];
    *(float2*)(sums + (size_t)cls * DIM + d0) = make_float2(s0, s1);
    const float cinv = 1.0f / fmaxf((float)cnt, 1.0f);
    const __bf16 c0 = (__bf16)(s0 * cinv);
    const __bf16 c1 = (__bf16)(s1 * cinv);
    ushort2 cpk;
    cpk.x = *(const ushort*)&c0;
    cpk.y = *(const ushort*)&c1;
    *(ushort2*)(centb + (size_t)cls * DIM + d0) = cpk;
}

// ---------- Kernel 5: MFMA GEMM, double-buffered single-barrier K-loop -----
//  * 2 col-phases of 256 cols (acc 64 regs) -> 3 blocks/CU
//  * ping-pong LDS buffers: next chunk's global loads issue BEFORE the MFMA
//    phase (vmcnt covered by MFMAs), stores go to idle buffer, ONE barrier
//    per chunk. Write buf[(i+1)&1] races nothing: its last readers finished
//    before the barrier that ended iteration i-1.
#define A_STRIDE 40
#define B_STRIDE 40
__global__ __launch_bounds__(256, 3) void fused_loss_kernel(
    const ushort* __restrict__ embb, const int* __restrict__ labels,
    const int* __restrict__ counts, const float* __restrict__ sums,
    const ushort* __restrict__ centb,
    const float* __restrict__ wp, const float* __restrict__ bp,
    float* __restrict__ loss_acc)
{
    __shared__ __align__(16) ushort A_lds[2][64 * A_STRIDE];    // 10 KB
    __shared__ __align__(16) ushort B_lds[2][256 * B_STRIDE];   // 40 KB
    __shared__ float m_part[4][64];
    __shared__ float s_part[4][64];
    __shared__ float ll_s[64];
    __shared__ float own_s[64];
    __shared__ int   lblrep_s[64];      // label | (rep<<16)

    const int tid  = threadIdx.x;
    const int wave = tid >> 6;
    const int lane = tid & 63;
    const int ln31 = lane & 31;
    const int half = lane >> 5;
    const int r0   = blockIdx.x * 64;

    m_part[wave][lane] = -1e30f;
    s_part[wave][lane] = 0.f;

    // ---- Phase A: leave-one-out own logit per row ----
    for (int rr = wave; rr < 64; rr += 4) {
        const int row = r0 + rr;
        const int l   = labels[row];
        const uint4 ev = *(const uint4*)(embb + (size_t)row * DIM + lane * 8);
        const ushort* eu = (const ushort*)&ev;
        const float4* sp = (const float4*)(sums + (size_t)l * DIM + lane * 8);
        const float4 s0 = sp[0], s1 = sp[1];
        const float sv[8] = {s0.x, s0.y, s0.z, s0.w, s1.x, s1.y, s1.z, s1.w};
        float d1 = 0.f, d2 = 0.f;
        #pragma unroll
        for (int jj = 0; jj < 8; ++jj) {
            const float e  = bf2f(eu[jj]);
            const float df = sv[jj] - e;
            d1 += e * df;
            d2 += df * df;
        }
        #pragma unroll
        for (int off = 32; off > 0; off >>= 1) {
            d1 += __shfl_down(d1, off, 64);
            d2 += __shfl_down(d2, off, 64);
        }
        if (lane == 0) {
            own_s[rr] = d1 / fmaxf(sqrtf(d2), 1e-12f);
            lblrep_s[rr] = l | ((counts[l] > 1) ? (1 << 16) : 0);
        }
    }
    __syncthreads();

    // ---- staging / fragment indices ----
    const int srow = tid >> 2;          // 0..63
    const int sch  = (tid & 3) * 8;     // k sub-offset
    const ushort* aSrc = embb + (size_t)(r0 + srow) * DIM + sch;
    const int aOff = srow * A_STRIDE + sch;
    const int bOff = srow * B_STRIDE + sch;
    const int ArdOff = ln31 * A_STRIDE + half * 8;
    const int BrdOff = (wave * 64 + ln31) * B_STRIDE + half * 8;

    const int rot = (blockIdx.x * 7) & 15;
    const float wv = fmaxf(wp[0], 1e-6f);
    const float bv = bp[0];

    #pragma unroll 1
    for (int ph = 0; ph < 2; ++ph) {
        const ushort* bSrc = centb + (size_t)(ph * 256 + srow) * DIM + sch;
        f32x16 acc[2][2] = {};

        uint4 aR, bR0, bR1, bR2, bR3;
        {   // prologue: chunk 0 -> buf 0
            const int kk = rot * 32;
            aR  = *(const uint4*)(aSrc + kk);
            bR0 = *(const uint4*)(bSrc + kk);
            bR1 = *(const uint4*)(bSrc + (size_t)64  * DIM + kk);
            bR2 = *(const uint4*)(bSrc + (size_t)128 * DIM + kk);
            bR3 = *(const uint4*)(bSrc + (size_t)192 * DIM + kk);
            *(uint4*)(A_lds[0] + aOff) = aR;
            *(uint4*)(B_lds[0] + bOff)                    = bR0;
            *(uint4*)(B_lds[0] + bOff +  64 * B_STRIDE)   = bR1;
            *(uint4*)(B_lds[0] + bOff + 128 * B_STRIDE)   = bR2;
            *(uint4*)(B_lds[0] + bOff + 192 * B_STRIDE)   = bR3;
        }
        __syncthreads();

        #pragma unroll 2
        for (int ic = 0; ic < 16; ++ic) {
            const int cur = ic & 1;
            // prefetch next chunk (global->reg), issued before MFMA phase
            if (ic < 15) {
                const int kk = ((ic + 1 + rot) & 15) * 32;
                aR  = *(const uint4*)(aSrc + kk);
                bR0 = *(const uint4*)(bSrc + kk);
                bR1 = *(const uint4*)(bSrc + (size_t)64  * DIM + kk);
                bR2 = *(const uint4*)(bSrc + (size_t)128 * DIM + kk);
                bR3 = *(const uint4*)(bSrc + (size_t)192 * DIM + kk);
            }
            // MFMA on current buffer
            const ushort* Ac = A_lds[cur] + ArdOff;
            const ushort* Bc = B_lds[cur] + BrdOff;
            #pragma unroll
            for (int ks = 0; ks < 2; ++ks) {
                const int ko = ks * 16;
                const bf16x8 a0 = *(const bf16x8*)(Ac + ko);
                const bf16x8 a1 = *(const bf16x8*)(Ac + 32 * A_STRIDE + ko);
                const bf16x8 b0 = *(const bf16x8*)(Bc + ko);
                const bf16x8 b1 = *(const bf16x8*)(Bc + 32 * B_STRIDE + ko);
                acc[0][0] = __builtin_amdgcn_mfma_f32_32x32x16_bf16(a0, b0, acc[0][0], 0, 0, 0);
                acc[0][1] = __builtin_amdgcn_mfma_f32_32x32x16_bf16(a0, b1, acc[0][1], 0, 0, 0);
                acc[1][0] = __builtin_amdgcn_mfma_f32_32x32x16_bf16(a1, b0, acc[1][0], 0, 0, 0);
                acc[1][1] = __builtin_amdgcn_mfma_f32_32x32x16_bf16(a1, b1, acc[1][1], 0, 0, 0);
            }
            // store prefetched chunk into idle buffer
            if (ic < 15) {
                const int nxt = cur ^ 1;
                *(uint4*)(A_lds[nxt] + aOff) = aR;
                *(uint4*)(B_lds[nxt] + bOff)                  = bR0;
                *(uint4*)(B_lds[nxt] + bOff +  64 * B_STRIDE) = bR1;
                *(uint4*)(B_lds[nxt] + bOff + 128 * B_STRIDE) = bR2;
                *(uint4*)(B_lds[nxt] + bOff + 192 * B_STRIDE) = bR3;
            }
            __syncthreads();
        }

        // ---- phase epilogue: merge 256 cols into running (m,s) ----
        #pragma unroll
        for (int mt = 0; mt < 2; ++mt) {
            #pragma unroll
            for (int reg = 0; reg < 16; ++reg) {
                const int row = mt * 32 + (reg & 3) + 8 * (reg >> 2) + 4 * half;
                const int lr  = lblrep_s[row];
                const int lbl = lr & 0xFFFF;
                float vals[2];
                float mx = -1e30f;
                #pragma unroll
                for (int jn = 0; jn < 2; ++jn) {
                    const int col = ph * 256 + wave * 64 + jn * 32 + ln31;
                    float lg = wv * acc[mt][jn][reg] + bv;
                    if (col == lbl) {
                        if (lr >> 16) lg = wv * own_s[row] + bv;
                        ll_s[row] = lg;
                    }
                    vals[jn] = lg;
                    mx = fmaxf(mx, lg);
                }
                #pragma unroll
                for (int off = 1; off < 32; off <<= 1)
                    mx = fmaxf(mx, __shfl_xor(mx, off, 64));
                float s = __expf(vals[0] - mx) + __expf(vals[1] - mx);
                #pragma unroll
                for (int off = 1; off < 32; off <<= 1)
                    s += __shfl_xor(s, off, 64);
                if (ln31 == 0) {
                    const float mo = m_part[wave][row];
                    const float mn = fmaxf(mo, mx);
                    s_part[wave][row] = s_part[wave][row] * __expf(mo - mn)
                                      + s * __expf(mx - mn);
                    m_part[wave][row] = mn;
                }
            }
        }
    }
    __syncthreads();

    if (tid < 64) {
        const int row = tid;
        float m0 = m_part[0][row], m1 = m_part[1][row];
        float m2 = m_part[2][row], m3 = m_part[3][row];
        float mt = fmaxf(fmaxf(m0, m1), fmaxf(m2, m3));
        float st = s_part[0][row] * __expf(m0 - mt)
                 + s_part[1][row] * __expf(m1 - mt)
                 + s_part[2][row] * __expf(m2 - mt)
                 + s_part[3][row] * __expf(m3 - mt);
        float loss = mt + __logf(st) - ll_s[row];
        #pragma unroll
        for (int off = 32; off > 0; off >>= 1)
            loss += __shfl_down(loss, off, 64);
        if (tid == 0) atomicAdd(loss_acc, loss);
    }
}

// ---------- Kernel 6: finalize ---------------------------------------------
__global__ void finalize_kernel(const float* __restrict__ acc, float* __restrict__ out)
{
    out[0] = acc[0] / (float)N_ROWS;
}

extern "C" void kernel_launch(void* const* d_in, const int* in_sizes, int n_in,
                              void* d_out, int out_size, void* d_ws, size_t ws_size,
                              hipStream_t stream)
{
    const float* emb    = (const float*)d_in[0];
    const int*   labels = (const int*)d_in[1];
    const float* wp     = (const float*)d_in[2];
    const float* bp     = (const float*)d_in[3];
    float* out = (float*)d_out;

    char* ws = (char*)d_ws;
    ushort* embb    = (ushort*)(ws + 0);              // 64 MiB
    int*    counts  = (int*)   (ws + 67108864);       // 2 KiB
    int*    offs    = (int*)   (ws + 67110912);       // 2 KiB
    int*    cursors = (int*)   (ws + 67112960);       // 2 KiB
    float*  loss_acc= (float*) (ws + 67115008);       // 256 B
    int*    order   = (int*)   (ws + 67115264);       // 256 KiB
    float*  sums    = (float*) (ws + 67377408);       // 1 MiB
    ushort* centb   = (ushort*)(ws + 68425728);       // 512 KiB

    hipMemsetAsync(counts, 0, KCLS * sizeof(int), stream);

    rnorm_embb_kernel<<<N_ROWS / 4, 256, 0, stream>>>(emb, labels, embb, counts);
    scan_kernel<<<1, 512, 0, stream>>>(counts, offs, cursors, loss_acc);
    scatter_kernel<<<N_ROWS / 256, 256, 0, stream>>>(labels, offs, cursors, order);
    class_sum_kernel<<<KCLS, 256, 0, stream>>>(embb, counts, offs, order, sums, centb);
    fused_loss_kernel<<<N_ROWS / 64, 256, 0, stream>>>(embb, labels, counts, sums,
                                                       centb, wp, bp, loss_acc);
    finalize_kernel<<<1, 1, 0, stream>>>(loss_acc, out);
}

// Round 8
// 333.846 us; speedup vs baseline: 1.1639x; 1.1639x over previous
//
#include <hip/hip_runtime.h>
#include <hip/hip_bf16.h>

#define N_ROWS 65536
#define DIM    512
#define KCLS   512
#define BUCKET 256   // padded per-class bucket for counting sort (max cnt ~170)

typedef __bf16 bf16x8 __attribute__((ext_vector_type(8)));
typedef float  f32x16 __attribute__((ext_vector_type(16)));

__device__ __forceinline__ float bf2f(ushort u) {
    union { unsigned int i; float f; } v; v.i = ((unsigned int)u) << 16; return v.f;
}

// ---------- Kernel 1: normalize -> bf16 embb + histogram + bucket scatter --
__global__ __launch_bounds__(256) void rnorm_embb_kernel(
    const float* __restrict__ emb, const int* __restrict__ labels,
    ushort* __restrict__ embb, int* __restrict__ counts,
    ushort* __restrict__ order16)
{
    const int tid  = threadIdx.x;
    const int wave = tid >> 6;
    const int lane = tid & 63;
    const int row  = blockIdx.x * 4 + wave;

    const float4* ep = (const float4*)(emb + (size_t)row * DIM + lane * 8);
    const float4 e0 = ep[0], e1 = ep[1];
    float ss = e0.x*e0.x + e0.y*e0.y + e0.z*e0.z + e0.w*e0.w
             + e1.x*e1.x + e1.y*e1.y + e1.z*e1.z + e1.w*e1.w;
    #pragma unroll
    for (int off = 1; off < 64; off <<= 1)
        ss += __shfl_xor(ss, off, 64);
    const float rn = 1.0f / fmaxf(sqrtf(ss), 1e-12f);

    bf16x8 h;
    h[0] = (__bf16)(e0.x * rn); h[1] = (__bf16)(e0.y * rn);
    h[2] = (__bf16)(e0.z * rn); h[3] = (__bf16)(e0.w * rn);
    h[4] = (__bf16)(e1.x * rn); h[5] = (__bf16)(e1.y * rn);
    h[6] = (__bf16)(e1.z * rn); h[7] = (__bf16)(e1.w * rn);
    *(bf16x8*)(embb + (size_t)row * DIM + lane * 8) = h;

    if (lane == 0) {
        const int l   = labels[row];
        const int pos = atomicAdd(&counts[l], 1);
        order16[l * BUCKET + pos] = (ushort)row;
    }
}

// ---------- Kernel 2: per-class sums & bf16 centroids ----------------------
__global__ __launch_bounds__(256) void class_sum_kernel(
    const ushort* __restrict__ embb,
    const int* __restrict__ counts, const ushort* __restrict__ order16,
    float* __restrict__ sums, ushort* __restrict__ centb)
{
    __shared__ float part[4][DIM];

    const int cls  = blockIdx.x;
    const int tid  = threadIdx.x;
    const int wave = tid >> 6;
    const int lane = tid & 63;
    const int cnt  = counts[cls];
    const int base = cls * BUCKET;
    const int d8   = lane * 8;

    float a[8] = {};
    float b2[8] = {};
    int j = wave;
    for (; j + 4 < cnt; j += 8) {       // 2 independent gather chains in flight
        const int r1 = order16[base + j];
        const int r2 = order16[base + j + 4];
        const uint4 u1 = *(const uint4*)(embb + (size_t)r1 * DIM + d8);
        const uint4 u2 = *(const uint4*)(embb + (size_t)r2 * DIM + d8);
        const ushort* s1 = (const ushort*)&u1;
        const ushort* s2 = (const ushort*)&u2;
        #pragma unroll
        for (int q = 0; q < 8; ++q) { a[q] += bf2f(s1[q]); b2[q] += bf2f(s2[q]); }
    }
    if (j < cnt) {
        const int r = order16[base + j];
        const uint4 u = *(const uint4*)(embb + (size_t)r * DIM + d8);
        const ushort* s1 = (const ushort*)&u;
        #pragma unroll
        for (int q = 0; q < 8; ++q) a[q] += bf2f(s1[q]);
    }
    #pragma unroll
    for (int q = 0; q < 8; ++q) part[wave][d8 + q] = a[q] + b2[q];
    __syncthreads();

    const int d0 = tid * 2;
    const float s0 = part[0][d0]   + part[1][d0]   + part[2][d0]   + part[3][d0];
    const float s1 = part[0][d0+1] + part[1][d0+1] + part[2][d0+1] + part[3][d0+1];
    *(float2*)(sums + (size_t)cls * DIM + d0) = make_float2(s0, s1);
    const float cinv = 1.0f / fmaxf((float)cnt, 1.0f);
    const __bf16 c0 = (__bf16)(s0 * cinv);
    const __bf16 c1 = (__bf16)(s1 * cinv);
    ushort2 cpk;
    cpk.x = *(const ushort*)&c0;
    cpk.y = *(const ushort*)&c1;
    *(ushort2*)(centb + (size_t)cls * DIM + d0) = cpk;
}

// ---------- Kernel 3: MFMA GEMM + own + logsumexp + loss + finalize --------
// Proven Round-6 structure: single-buffer two-barrier K-loop, 2 col-phases
// of 256 cols (acc 64 regs), K rotation. Finalize fused via done-counter.
#define A_STRIDE 40   // 32 k + 8 pad (bf16 elems)
#define B_STRIDE 40
__global__ __launch_bounds__(256, 3) void fused_loss_kernel(
    const ushort* __restrict__ embb, const int* __restrict__ labels,
    const int* __restrict__ counts, const float* __restrict__ sums,
    const ushort* __restrict__ centb,
    const float* __restrict__ wp, const float* __restrict__ bp,
    float* __restrict__ loss_acc, int* __restrict__ done,
    float* __restrict__ out)
{
    __shared__ __align__(16) ushort A_lds[64 * A_STRIDE];    // 5 KB
    __shared__ __align__(16) ushort B_lds[256 * B_STRIDE];   // 20 KB
    __shared__ float m_part[4][64];
    __shared__ float s_part[4][64];
    __shared__ float ll_s[64];
    __shared__ float own_s[64];
    __shared__ int   lbl_s[64];
    __shared__ int   rep_s[64];

    const int tid  = threadIdx.x;
    const int wave = tid >> 6;
    const int lane = tid & 63;
    const int ln31 = lane & 31;
    const int half = lane >> 5;
    const int r0   = blockIdx.x * 64;

    m_part[wave][lane] = -1e30f;
    s_part[wave][lane] = 0.f;

    // ---- Phase A: leave-one-out own logit per row ----
    for (int rr = wave; rr < 64; rr += 4) {
        const int row = r0 + rr;
        const int l   = labels[row];
        const uint4 ev = *(const uint4*)(embb + (size_t)row * DIM + lane * 8);
        const ushort* eu = (const ushort*)&ev;
        const float4* sp = (const float4*)(sums + (size_t)l * DIM + lane * 8);
        const float4 s0 = sp[0], s1 = sp[1];
        const float sv[8] = {s0.x, s0.y, s0.z, s0.w, s1.x, s1.y, s1.z, s1.w};
        float d1 = 0.f, d2 = 0.f;
        #pragma unroll
        for (int jj = 0; jj < 8; ++jj) {
            const float e  = bf2f(eu[jj]);
            const float df = sv[jj] - e;
            d1 += e * df;
            d2 += df * df;
        }
        #pragma unroll
        for (int off = 32; off > 0; off >>= 1) {
            d1 += __shfl_down(d1, off, 64);
            d2 += __shfl_down(d2, off, 64);
        }
        if (lane == 0) {
            own_s[rr] = d1 / fmaxf(sqrtf(d2), 1e-12f);
            lbl_s[rr] = l;
            rep_s[rr] = (counts[l] > 1) ? 1 : 0;
        }
    }
    __syncthreads();

    // ---- staging / fragment pointers ----
    const int srow = tid >> 2;          // 0..63
    const int sch  = (tid & 3) * 8;     // k sub-offset
    const ushort* aSrc = embb + (size_t)(r0 + srow) * DIM + sch;
    ushort* aDst = A_lds + srow * A_STRIDE + sch;
    ushort* bDst = B_lds + srow * B_STRIDE + sch;
    const ushort* Ard = A_lds + ln31 * A_STRIDE + half * 8;
    const ushort* Brd = B_lds + (wave * 64 + ln31) * B_STRIDE + half * 8;

    const int rot = (blockIdx.x * 7) & 15;   // K-schedule rotation
    const float wv = fmaxf(wp[0], 1e-6f);
    const float bv = bp[0];

    #pragma unroll 1
    for (int ph = 0; ph < 2; ++ph) {
        const ushort* bBase = centb + (size_t)(ph * 256) * DIM;
        f32x16 acc[2][2] = {};

        #pragma unroll 1
        for (int ic = 0; ic < 16; ++ic) {
            const int kk = ((ic + rot) & 15) * 32;
            *(uint4*)aDst = *(const uint4*)(aSrc + kk);
            #pragma unroll
            for (int it = 0; it < 4; ++it)
                *(uint4*)(bDst + it * 64 * B_STRIDE) =
                    *(const uint4*)(bBase + (size_t)(srow + it * 64) * DIM + sch + kk);
            __syncthreads();

            #pragma unroll
            for (int ks = 0; ks < 2; ++ks) {
                const int ko = ks * 16;
                const bf16x8 a0 = *(const bf16x8*)(Ard + ko);
                const bf16x8 a1 = *(const bf16x8*)(Ard + 32 * A_STRIDE + ko);
                const bf16x8 b0 = *(const bf16x8*)(Brd + ko);
                const bf16x8 b1 = *(const bf16x8*)(Brd + 32 * B_STRIDE + ko);
                acc[0][0] = __builtin_amdgcn_mfma_f32_32x32x16_bf16(a0, b0, acc[0][0], 0, 0, 0);
                acc[0][1] = __builtin_amdgcn_mfma_f32_32x32x16_bf16(a0, b1, acc[0][1], 0, 0, 0);
                acc[1][0] = __builtin_amdgcn_mfma_f32_32x32x16_bf16(a1, b0, acc[1][0], 0, 0, 0);
                acc[1][1] = __builtin_amdgcn_mfma_f32_32x32x16_bf16(a1, b1, acc[1][1], 0, 0, 0);
            }
            __syncthreads();
        }

        // ---- phase epilogue: merge this phase's 256 cols into running (m,s) ----
        #pragma unroll
        for (int mt = 0; mt < 2; ++mt) {
            #pragma unroll
            for (int reg = 0; reg < 16; ++reg) {
                const int row = mt * 32 + (reg & 3) + 8 * (reg >> 2) + 4 * half;
                const int lbl = lbl_s[row];
                float vals[2];
                float mx = -1e30f;
                #pragma unroll
                for (int jn = 0; jn < 2; ++jn) {
                    const int col = ph * 256 + wave * 64 + jn * 32 + ln31;
                    float lg = wv * acc[mt][jn][reg] + bv;
                    if (col == lbl) {
                        if (rep_s[row]) lg = wv * own_s[row] + bv;
                        ll_s[row] = lg;
                    }
                    vals[jn] = lg;
                    mx = fmaxf(mx, lg);
                }
                #pragma unroll
                for (int off = 1; off < 32; off <<= 1)
                    mx = fmaxf(mx, __shfl_xor(mx, off, 64));
                float s = __expf(vals[0] - mx) + __expf(vals[1] - mx);
                #pragma unroll
                for (int off = 1; off < 32; off <<= 1)
                    s += __shfl_xor(s, off, 64);
                if (ln31 == 0) {
                    const float mo = m_part[wave][row];
                    const float mn = fmaxf(mo, mx);
                    s_part[wave][row] = s_part[wave][row] * __expf(mo - mn)
                                      + s * __expf(mx - mn);
                    m_part[wave][row] = mn;
                }
            }
        }
    }
    __syncthreads();

    if (tid < 64) {
        const int row = tid;
        float m0 = m_part[0][row], m1 = m_part[1][row];
        float m2 = m_part[2][row], m3 = m_part[3][row];
        float mt = fmaxf(fmaxf(m0, m1), fmaxf(m2, m3));
        float st = s_part[0][row] * __expf(m0 - mt)
                 + s_part[1][row] * __expf(m1 - mt)
                 + s_part[2][row] * __expf(m2 - mt)
                 + s_part[3][row] * __expf(m3 - mt);
        float loss = mt + __logf(st) - ll_s[row];
        #pragma unroll
        for (int off = 32; off > 0; off >>= 1)
            loss += __shfl_down(loss, off, 64);
        if (tid == 0) {
            atomicAdd(loss_acc, loss);
            __threadfence();
            const int t = atomicAdd(done, 1);
            if (t == (N_ROWS / 64) - 1) {
                const float tot = atomicAdd(loss_acc, 0.0f);  // coherent read
                out[0] = tot / (float)N_ROWS;
            }
        }
    }
}

extern "C" void kernel_launch(void* const* d_in, const int* in_sizes, int n_in,
                              void* d_out, int out_size, void* d_ws, size_t ws_size,
                              hipStream_t stream)
{
    const float* emb    = (const float*)d_in[0];
    const int*   labels = (const int*)d_in[1];
    const float* wp     = (const float*)d_in[2];
    const float* bp     = (const float*)d_in[3];
    float* out = (float*)d_out;

    char* ws = (char*)d_ws;
    ushort* embb    = (ushort*)(ws + 0);              // 64 MiB
    ushort* order16 = (ushort*)(ws + 67108864);       // 512*256*2 = 256 KiB
    float*  sums    = (float*) (ws + 67371008);       // 1 MiB
    ushort* centb   = (ushort*)(ws + 68419584);       // 512 KiB
    int*    counts  = (int*)   (ws + 68943872);       // 2048 B
    float*  loss_acc= (float*) (ws + 68945920);       // 4 B
    int*    done    = (int*)   (ws + 68945924);       // 4 B

    // zero counts + loss_acc + done in one memset (contiguous 2056 B)
    hipMemsetAsync(counts, 0, 2056, stream);

    rnorm_embb_kernel<<<N_ROWS / 4, 256, 0, stream>>>(emb, labels, embb, counts, order16);
    class_sum_kernel<<<KCLS, 256, 0, stream>>>(embb, counts, order16, sums, centb);
    fused_loss_kernel<<<N_ROWS / 64, 256, 0, stream>>>(embb, labels, counts, sums,
                                                       centb, wp, bp, loss_acc, done, out);
}